// Round 1
// baseline (807.940 us; speedup 1.0000x reference)
//
#include <hip/hip_runtime.h>
#include <hip/hip_bf16.h>
#include <math.h>

typedef __attribute__((ext_vector_type(4))) float f32x4;
typedef __attribute__((ext_vector_type(8))) short bf16x8;

#define M_TOT   8192
#define OFF_MCONF 33554432LL                 // 8192*4096
#define OFF_MK0   33562624LL
#define OFF_MK1   33579008LL
#define OFF_VALID 33595392LL
#define SIM_SCALE 0.10416666666666667f       // 1/(96*0.1)

__device__ __forceinline__ short f2bf(float v) {
    __hip_bfloat16 h = __float2bfloat16(v);
    return *reinterpret_cast<short*>(&h);
}

// ---------------------------------------------------------------------------
// K0: repack w1/w2 (oc,ic,ky,kx) f32 -> (oc, q=ky*3+kx, ic) bf16  (GEMM-B^T)
// ---------------------------------------------------------------------------
__global__ void wprep(const float* __restrict__ w1, const float* __restrict__ w2,
                      short* __restrict__ o1, short* __restrict__ o2) {
    int i = blockIdx.x * 256 + threadIdx.x;
    if (i >= 2 * 331776) return;
    const float* src = (i < 331776) ? w1 : w2;
    short* dst       = (i < 331776) ? o1 : o2;
    int o = (i < 331776) ? i : i - 331776;
    int oc = o / 1728, r = o % 1728;
    int q = r / 192, ic = r % 192;
    dst[o] = f2bf(src[oc * 1728 + ic * 9 + q]);
}

// ---------------------------------------------------------------------------
// K1: per-m 64x64 sim (fp32), conf = softmax_l * softmax_s, conf write,
//     argmax -> mconf/valid outputs + mk0/mk1 integer coords to workspace.
//     One block per m; thread t owns 4x4 strided tile l=lg+16i, s=sg+16j.
// ---------------------------------------------------------------------------
__global__ __launch_bounds__(256) void stageA(const float* __restrict__ f0u,
                                              const float* __restrict__ f1u,
                                              const int* __restrict__ i_ids_c,
                                              const int* __restrict__ j_ids_c,
                                              float* __restrict__ out,
                                              int* __restrict__ mkws) {
    __shared__ float f0L[64 * 100];   // row stride 100: b128-aligned, 2-way banks max
    __shared__ float f1L[64 * 100];
    __shared__ float Rpart[16 * 64];  // [sg][l]  partial row sums (over s)
    __shared__ float Cpart[16 * 64];  // [lg][s]  partial col sums (over l)
    __shared__ float invR[64], invC[64];
    __shared__ float rv[256];
    __shared__ int   ri[256];

    const int m = blockIdx.x;
    const int t = threadIdx.x;
    const int lg = t >> 4, sg = t & 15;

    const float* g0 = f0u + (size_t)m * 6144;
    const float* g1 = f1u + (size_t)m * 6144;
    for (int v = t; v < 1536; v += 256) {
        int l = v / 24, c4 = (v % 24) * 4;
        *(f32x4*)&f0L[l * 100 + c4] = *(const f32x4*)(g0 + v * 4);
        *(f32x4*)&f1L[l * 100 + c4] = *(const f32x4*)(g1 + v * 4);
    }
    __syncthreads();

    float acc[4][4] = {};
#pragma unroll 2
    for (int k = 0; k < 96; k += 4) {
        f32x4 a[4], b[4];
#pragma unroll
        for (int i = 0; i < 4; ++i) a[i] = *(const f32x4*)&f0L[(lg + 16 * i) * 100 + k];
#pragma unroll
        for (int j = 0; j < 4; ++j) b[j] = *(const f32x4*)&f1L[(sg + 16 * j) * 100 + k];
#pragma unroll
        for (int i = 0; i < 4; ++i)
#pragma unroll
            for (int j = 0; j < 4; ++j) {
                acc[i][j] += a[i].x * b[j].x;
                acc[i][j] += a[i].y * b[j].y;
                acc[i][j] += a[i].z * b[j].z;
                acc[i][j] += a[i].w * b[j].w;
            }
    }

    float e[4][4];
    float rp[4] = {0.f, 0.f, 0.f, 0.f}, cp[4] = {0.f, 0.f, 0.f, 0.f};
#pragma unroll
    for (int i = 0; i < 4; ++i)
#pragma unroll
        for (int j = 0; j < 4; ++j) {
            float v = __expf(acc[i][j] * SIM_SCALE);
            e[i][j] = v;
            rp[i] += v;
            cp[j] += v;
        }
#pragma unroll
    for (int i = 0; i < 4; ++i) Rpart[sg * 64 + lg + 16 * i] = rp[i];
#pragma unroll
    for (int j = 0; j < 4; ++j) Cpart[lg * 64 + sg + 16 * j] = cp[j];
    __syncthreads();
    if (t < 64) {
        float sR = 0.f, sC = 0.f;
#pragma unroll
        for (int g = 0; g < 16; ++g) { sR += Rpart[g * 64 + t]; sC += Cpart[g * 64 + t]; }
        invR[t] = 1.0f / sR;   // softmax over s (axis=2) denominator, indexed by l
        invC[t] = 1.0f / sC;   // softmax over l (axis=1) denominator, indexed by s
    }
    __syncthreads();

    float bestv = -1.0f;
    int besti = 0;
    float* cbase = out + (size_t)m * 4096;
#pragma unroll
    for (int i = 0; i < 4; ++i) {
        int l = lg + 16 * i;
        float iR = invR[l];
#pragma unroll
        for (int j = 0; j < 4; ++j) {
            int s = sg + 16 * j;
            float c = (e[i][j] * iR) * (e[i][j] * invC[s]);
            cbase[l * 64 + s] = c;
            int fi = l * 64 + s;
            if (c > bestv || (c == bestv && fi < besti)) { bestv = c; besti = fi; }
        }
    }
    rv[t] = bestv; ri[t] = besti;
    __syncthreads();
    if (t < 64) {
#pragma unroll
        for (int g = 1; g < 4; ++g) {
            float v = rv[t + 64 * g]; int idx = ri[t + 64 * g];
            if (v > rv[t] || (v == rv[t] && idx < ri[t])) { rv[t] = v; ri[t] = idx; }
        }
    }
    __syncthreads();
    if (t == 0) {
        float bv = rv[0]; int bi = ri[0];
        for (int g = 1; g < 64; ++g) {
            float v = rv[g]; int idx = ri[g];
            if (v > bv || (v == bv && idx < bi)) { bv = v; bi = idx; }
        }
        bool valid = bv > 0.01f;
        out[OFF_MCONF + m] = valid ? bv : 0.0f;
        out[OFF_VALID + m] = valid ? 1.0f : 0.0f;
        int il = bi >> 6, js = bi & 63;
        int ic0 = i_ids_c[m], jc0 = j_ids_c[m];
        mkws[m * 4 + 0] = (ic0 % 80) * 4 + (il & 7) - 4;   // mk0 x
        mkws[m * 4 + 1] = (ic0 / 80) * 4 + (il >> 3) - 4;  // mk0 y
        mkws[m * 4 + 2] = (jc0 % 80) * 4 + (js & 7) - 4;   // mk1 x
        mkws[m * 4 + 3] = (jc0 / 80) * 4 + (js >> 3) - 4;  // mk1 y
    }
}

// ---------------------------------------------------------------------------
// K2: fused gather + conv1(3x3,pad1) + conv2(3x3,valid) + conv3(1x1) + tanh.
// 16 matches per block. Patches in LDS as [m][slot 0..9][ic(192), stride 200]
// bf16 (slot 9 = zero row for im2col padding). conv1 = 144x192 GEMM, K=1728
// in q-major order; conv2 reuses LDS in-place as [row=m*9+p][oc, stride 200].
// ---------------------------------------------------------------------------
__global__ __launch_bounds__(256, 2) void stageB(const float* __restrict__ w0whole,
                                                 const float* __restrict__ w1whole,
                                                 const int* __restrict__ bids,
                                                 const int* __restrict__ mkws,
                                                 const short* __restrict__ w1b,
                                                 const short* __restrict__ w2b,
                                                 const float* __restrict__ w3,
                                                 float* __restrict__ out) {
    __shared__ short bufA[32000];        // 64 KB: patches, then conv1 output
    __shared__ float bufC[16 * 196];     // conv2 output (padded stride 196)
    __shared__ float xout[64];

    const int t = threadIdx.x;
    const int m0 = blockIdx.x * 16;
    const int lane = t & 63, wv = t >> 6;
    const int l16 = lane & 15, quad = lane >> 4;
    const int colb = wv * 48;

    // zero-slot (slot 9) per m
    for (int v = t; v < 16 * 200; v += 256) {
        int mm = v / 200, c = v % 200;
        bufA[mm * 2000 + 1800 + c] = 0;
    }
    // gather: 16 m * 2 img * 96 c * 3 dy = 9216 3-float row segments
    for (int seg = t; seg < 9216; seg += 256) {
        int c = seg % 96;
        int r = seg / 96;
        int dy = r % 3;
        int mi = r / 3;
        int img = mi & 1;
        int m_loc = mi >> 1;
        int mg = m0 + m_loc;
        int b = bids[mg];
        int mkx = mkws[mg * 4 + img * 2 + 0];
        int mky = mkws[mg * 4 + img * 2 + 1];
        int y = mky + dy - 1;
        const float* src = (img ? w1whole : w0whole) + (((size_t)b * 96 + c) * 320 + y) * 320;
        bool yok = (unsigned)y < 320u;
        short* dst = &bufA[m_loc * 2000 + dy * 3 * 200 + img * 96 + c];
#pragma unroll
        for (int dx = 0; dx < 3; ++dx) {
            int x = mkx + dx - 1;
            float v = (yok && (unsigned)x < 320u) ? src[x] : 0.0f;
            dst[dx * 200] = f2bf(v);
        }
    }
    __syncthreads();

    // ---- conv1: GEMM rows=(m*9+p) 144, cols=oc 192, K=(q,ic) 1728 ----
    int mbase[9], py[9], px[9];
#pragma unroll
    for (int rt = 0; rt < 9; ++rt) {
        int row = rt * 16 + l16;
        int mm = row / 9;
        int p = row - mm * 9;
        mbase[rt] = mm * 2000;
        py[rt] = p / 3;
        px[rt] = p - py[rt] * 3;
    }
    f32x4 acc1[9][3] = {};
#pragma unroll
    for (int q = 0; q < 9; ++q) {
        const int qy = q / 3, qx = q % 3;
        int aoff[9];
#pragma unroll
        for (int rt = 0; rt < 9; ++rt) {
            int y = py[rt] + qy - 1, x = px[rt] + qx - 1;
            bool ok = ((unsigned)y < 3u) && ((unsigned)x < 3u);
            int slot = ok ? (y * 3 + x) : 9;
            aoff[rt] = mbase[rt] + slot * 200 + quad * 8;
        }
#pragma unroll
        for (int kk = 0; kk < 6; ++kk) {
            const int kg = q * 192 + kk * 32 + quad * 8;
            bf16x8 bfr[3];
#pragma unroll
            for (int ct = 0; ct < 3; ++ct) {
                int n = colb + ct * 16 + l16;
                bfr[ct] = *(const bf16x8*)(w1b + n * 1728 + kg);
            }
            bf16x8 afr[9];
#pragma unroll
            for (int rt = 0; rt < 9; ++rt)
                afr[rt] = *(const bf16x8*)&bufA[aoff[rt] + kk * 32];
#pragma unroll
            for (int rt = 0; rt < 9; ++rt)
#pragma unroll
                for (int ct = 0; ct < 3; ++ct)
                    acc1[rt][ct] = __builtin_amdgcn_mfma_f32_16x16x32_bf16(
                        afr[rt], bfr[ct], acc1[rt][ct], 0, 0, 0);
        }
    }
    __syncthreads();
    // leaky-relu, bf16, store as [row][oc] stride 200 (in-place over patches)
#pragma unroll
    for (int rt = 0; rt < 9; ++rt)
#pragma unroll
        for (int ct = 0; ct < 3; ++ct)
#pragma unroll
            for (int r = 0; r < 4; ++r) {
                int row = rt * 16 + quad * 4 + r;
                int col = colb + ct * 16 + l16;
                float v = acc1[rt][ct][r];
                v = (v > 0.f) ? v : 0.01f * v;
                bufA[row * 200 + col] = f2bf(v);
            }
    __syncthreads();

    // ---- conv2: rows=m 16, cols=oc2 192, K=(p,ic2) 1728 ----
    f32x4 acc2[3] = {};
#pragma unroll 6
    for (int ks = 0; ks < 54; ++ks) {
        int k = ks * 32 + quad * 8;
        int p = k / 192;
        int ic = k - p * 192;
        bf16x8 a = *(const bf16x8*)&bufA[l16 * 1800 + p * 200 + ic];
#pragma unroll
        for (int ct = 0; ct < 3; ++ct) {
            int n = colb + ct * 16 + l16;
            bf16x8 b = *(const bf16x8*)(w2b + n * 1728 + k);
            acc2[ct] = __builtin_amdgcn_mfma_f32_16x16x32_bf16(a, b, acc2[ct], 0, 0, 0);
        }
    }
#pragma unroll
    for (int ct = 0; ct < 3; ++ct)
#pragma unroll
        for (int r = 0; r < 4; ++r) {
            int mrow = quad * 4 + r;
            int col = colb + ct * 16 + l16;
            float v = acc2[ct][r];
            v = (v > 0.f) ? v : 0.01f * v;
            bufC[mrow * 196 + col] = v;
        }
    __syncthreads();

    // ---- conv3 (1x1, 4 out channels) ----
    if (t < 64) {
        int mloc = t >> 2, j = t & 3;
        const float* wr = w3 + j * 192;
        const float* xr = &bufC[mloc * 196];
        float d = 0.f;
        for (int c = 0; c < 192; ++c) d += xr[c] * wr[c];
        xout[t] = d;
    }
    __syncthreads();
    if (t < 16) {
        int mg = m0 + t;
        float s0x = tanhf(xout[t * 4 + 0]) * 0.5f;
        float s0y = tanhf(xout[t * 4 + 1]) * 0.5f;
        float s1x = tanhf(xout[t * 4 + 2]) * 0.5f;
        float s1y = tanhf(xout[t * 4 + 3]) * 0.5f;
        float mk0x = (float)mkws[mg * 4 + 0], mk0y = (float)mkws[mg * 4 + 1];
        float mk1x = (float)mkws[mg * 4 + 2], mk1y = (float)mkws[mg * 4 + 3];
        out[OFF_MK0 + mg * 2 + 0] = (mk0x + s0x) * 2.0f;
        out[OFF_MK0 + mg * 2 + 1] = (mk0y + s0y) * 2.0f;
        out[OFF_MK1 + mg * 2 + 0] = (mk1x + s1x) * 2.0f;
        out[OFF_MK1 + mg * 2 + 1] = (mk1y + s1y) * 2.0f;
    }
}

extern "C" void kernel_launch(void* const* d_in, const int* in_sizes, int n_in,
                              void* d_out, int out_size, void* d_ws, size_t ws_size,
                              hipStream_t stream) {
    const float* f0u = (const float*)d_in[0];
    const float* f1u = (const float*)d_in[1];
    const float* f0w = (const float*)d_in[2];
    const float* f1w = (const float*)d_in[3];
    const int* bids  = (const int*)d_in[4];
    const int* iids  = (const int*)d_in[5];
    const int* jids  = (const int*)d_in[6];
    const float* w1  = (const float*)d_in[7];
    const float* w2  = (const float*)d_in[8];
    const float* w3  = (const float*)d_in[9];
    float* out = (float*)d_out;
    char* ws = (char*)d_ws;
    int* mkws  = (int*)ws;                          // 131072 B
    short* w1b = (short*)(ws + 131072);             // 663552 B
    short* w2b = (short*)(ws + 131072 + 663552);    // 663552 B

    wprep<<<dim3(2592), dim3(256), 0, stream>>>(w1, w2, w1b, w2b);
    stageA<<<dim3(8192), dim3(256), 0, stream>>>(f0u, f1u, iids, jids, out, mkws);
    stageB<<<dim3(512), dim3(256), 0, stream>>>(f0w, f1w, bids, mkws, w1b, w2b, w3, out);
}